// Round 9
// baseline (37.127 us; speedup 1.0000x reference)
//
#include <hip/hip_runtime.h>

#define DIM 128
#define CA  32          // edge chunks, degree histogram
#define RA  2           // node ranges (u16-packed, 25000 = 50KB LDS)
#define NA  25000
#define HB  (CA * RA)   // 64 hist blocks in k1
#define CB  16          // edge chunks, weighted scatter
#define RB  16          // node ranges (2 x 3125 f32 = 25KB LDS)
#define NB  3125

// K1 (fused): blocks [0,HB) build the u16-packed degree histogram of col
// (int4 edge scan); remaining blocks compute s[i] = dot(x[i], a1).
__global__ __launch_bounds__(1024) void k1_hist_s(
        const float* __restrict__ x, const float* __restrict__ a1,
        const int* __restrict__ col, ushort* __restrict__ pA,
        float* __restrict__ s, int E, int N) {
    __shared__ unsigned h[NA / 2];            // 50KB
    if (blockIdx.x < HB) {
        int c  = blockIdx.x % CA;
        int rg = blockIdx.x / CA;
        int lo = rg * NA;
        for (int j = threadIdx.x; j < NA / 2; j += 1024) h[j] = 0u;
        __syncthreads();
        int per = (((E + CA - 1) / CA) + 3) & ~3;        // x4-aligned chunks
        int e0 = c * per;
        int e1 = e0 + per; if (e1 > E) e1 = E;
        for (int e = e0 + threadIdx.x * 4; e < e1; e += 1024 * 4) {
            if (e + 4 <= e1) {
                int4 cv = *(const int4*)(col + e);
                unsigned i0 = (unsigned)(cv.x - lo), i1 = (unsigned)(cv.y - lo);
                unsigned i2 = (unsigned)(cv.z - lo), i3 = (unsigned)(cv.w - lo);
                if (i0 < (unsigned)NA) atomicAdd(&h[i0 >> 1], 1u << ((i0 & 1) * 16));
                if (i1 < (unsigned)NA) atomicAdd(&h[i1 >> 1], 1u << ((i1 & 1) * 16));
                if (i2 < (unsigned)NA) atomicAdd(&h[i2 >> 1], 1u << ((i2 & 1) * 16));
                if (i3 < (unsigned)NA) atomicAdd(&h[i3 >> 1], 1u << ((i3 & 1) * 16));
            } else {
                for (int ee = e; ee < e1; ++ee) {
                    unsigned idx = (unsigned)(col[ee] - lo);
                    if (idx < (unsigned)NA)
                        atomicAdd(&h[idx >> 1], 1u << ((idx & 1) * 16));
                }
            }
        }
        __syncthreads();
        unsigned* dst = (unsigned*)(pA + (size_t)c * N + lo);   // lo, N even
        for (int j = threadIdx.x; j < NA / 2; j += 1024) dst[j] = h[j];
    } else {
        int lw   = threadIdx.x >> 6;          // 16 waves, 2 rows each
        int lane = threadIdx.x & 63;
        int j    = lane & 31;
        int r = ((int)blockIdx.x - HB) * 32 + lw * 2 + (lane >> 5);
        if (r >= N) return;
        float4 xv = ((const float4*)x)[(size_t)r * 32 + j];
        float4 av = ((const float4*)a1)[j];
        float p = xv.x * av.x + xv.y * av.y + xv.z * av.z + xv.w * av.w;
        #pragma unroll
        for (int off = 16; off > 0; off >>= 1)
            p += __shfl_xor(p, off, 64);
        if (j == 0) s[r] = p;
    }
}

// K2: deg = 1 + sum_c pA (u32-packed, 2 nodes/thread); sd = (dis, dis*s)
__global__ void k_combine(const ushort* __restrict__ pA, const float* __restrict__ s,
                          float2* __restrict__ sd, int N) {
    int i2 = blockIdx.x * blockDim.x + threadIdx.x;
    if (i2 >= N / 2) return;
    unsigned d0 = 1u, d1 = 1u;                // self-loops
    #pragma unroll 8
    for (int c = 0; c < CA; ++c) {
        unsigned w = *(const unsigned*)&pA[(size_t)c * N + 2 * i2];
        d0 += w & 0xffffu; d1 += w >> 16;
    }
    float dv0 = rsqrtf((float)d0), dv1 = rsqrtf((float)d1);
    sd[2 * i2]     = make_float2(dv0, dv0 * s[2 * i2]);
    sd[2 * i2 + 1] = make_float2(dv1, dv1 * s[2 * i2 + 1]);
}

// K3: weighted scatter, int4 edge scan. Block (c,rg): LDS accumulate
// up += dis[c], vp += sdis[c] for edges with row in range; coalesced writeback.
__global__ __launch_bounds__(1024) void k_histB(const int* __restrict__ row,
                                                const int* __restrict__ col,
                                                const float2* __restrict__ sd,
                                                float2* __restrict__ pB,
                                                int E, int N) {
    __shared__ float up[NB];
    __shared__ float vp[NB];
    int c  = blockIdx.x % CB;
    int rg = blockIdx.x / CB;
    int lo = rg * NB;
    for (int j = threadIdx.x; j < NB; j += 1024) { up[j] = 0.f; vp[j] = 0.f; }
    __syncthreads();
    int per = (((E + CB - 1) / CB) + 3) & ~3;
    int e0 = c * per;
    int e1 = e0 + per; if (e1 > E) e1 = E;
    for (int e = e0 + threadIdx.x * 4; e < e1; e += 1024 * 4) {
        if (e + 4 <= e1) {
            int4 rv = *(const int4*)(row + e);
            int4 cv = *(const int4*)(col + e);
            unsigned i0 = (unsigned)(rv.x - lo), i1 = (unsigned)(rv.y - lo);
            unsigned i2 = (unsigned)(rv.z - lo), i3 = (unsigned)(rv.w - lo);
            if (i0 < (unsigned)NB) { float2 v = sd[cv.x]; atomicAdd(&up[i0], v.x); atomicAdd(&vp[i0], v.y); }
            if (i1 < (unsigned)NB) { float2 v = sd[cv.y]; atomicAdd(&up[i1], v.x); atomicAdd(&vp[i1], v.y); }
            if (i2 < (unsigned)NB) { float2 v = sd[cv.z]; atomicAdd(&up[i2], v.x); atomicAdd(&vp[i2], v.y); }
            if (i3 < (unsigned)NB) { float2 v = sd[cv.w]; atomicAdd(&up[i3], v.x); atomicAdd(&vp[i3], v.y); }
        } else {
            for (int ee = e; ee < e1; ++ee) {
                unsigned idx = (unsigned)(row[ee] - lo);
                if (idx < (unsigned)NB) {
                    float2 v = sd[col[ee]];
                    atomicAdd(&up[idx], v.x);
                    atomicAdd(&vp[idx], v.y);
                }
            }
        }
    }
    __syncthreads();
    float2* dst = pB + (size_t)c * N + lo;    // RB*NB == N exactly
    for (int j = threadIdx.x; j < NB; j += 1024)
        dst[j] = make_float2(up[j], vp[j]);
}

// K4: two-phase. Phase 1: thread i reduces node i over CB copies (coalesced),
// T/W -> LDS. Phase 2: 32-lane groups write whole 512B rows as float4.
__global__ __launch_bounds__(256) void k_out(
        const float2* __restrict__ pB, const float2* __restrict__ sd,
        const float* __restrict__ a2, const float* __restrict__ bias,
        float* __restrict__ out, int N) {
    __shared__ float sT[256];
    __shared__ float sW[256];
    int base = blockIdx.x * 256;
    int i = base + threadIdx.x;
    if (i < N) {
        float su = 0.f, sv = 0.f;
        #pragma unroll
        for (int c = 0; c < CB; ++c) {
            float2 p = pB[(size_t)c * N + i];
            su += p.x; sv += p.y;
        }
        float2 d = sd[i];
        sT[threadIdx.x] = d.x * (sv + d.y);   // + self-loop dis*sdis
        sW[threadIdx.x] = d.x * (su + d.x);   // + self-loop dis*dis
    }
    __syncthreads();
    int j   = threadIdx.x & 31;
    int grp = threadIdx.x >> 5;               // 8 groups of 32 lanes
    float4 a2v = ((const float4*)a2)[j];
    float4 bv  = ((const float4*)bias)[j];
    #pragma unroll 4
    for (int rep = 0; rep < 32; ++rep) {
        int rl = rep * 8 + grp;
        int node = base + rl;
        if (node >= N) break;
        float T = sT[rl], W = sW[rl];
        float4 o;
        o.x = a2v.x * T + bv.x * W;
        o.y = a2v.y * T + bv.y * W;
        o.z = a2v.z * T + bv.z * W;
        o.w = a2v.w * T + bv.w * W;
        ((float4*)out)[(size_t)node * 32 + j] = o;
    }
}

extern "C" void kernel_launch(void* const* d_in, const int* in_sizes, int n_in,
                              void* d_out, int out_size, void* d_ws, size_t ws_size,
                              hipStream_t stream) {
    const float* x    = (const float*)d_in[0];
    const int*   ei   = (const int*)d_in[1];
    const float* a1   = (const float*)d_in[2];
    const float* a2   = (const float*)d_in[3];
    const float* bias = (const float*)d_in[4];
    float* out = (float*)d_out;

    int N = in_sizes[0] / DIM;   // 50000
    int E = in_sizes[1] / 2;     // 600000
    const int* row = ei;         // edge_index[0]
    const int* col = ei + E;     // edge_index[1]

    // workspace: s[N] f32, sd[N] float2, pA[CA*N] u16, pB[CB*N] float2 (~10.2MB)
    float*  s  = (float*)d_ws;
    float2* sd = (float2*)(s + N);
    ushort* pA = (ushort*)(sd + N);
    float2* pB = (float2*)(pA + (size_t)CA * N);

    int s_blocks = (N + 31) / 32;             // 32 rows per 1024-thread block
    k1_hist_s<<<HB + s_blocks, 1024, 0, stream>>>(x, a1, col, pA, s, E, N);
    k_combine<<<(N / 2 + 255) / 256, 256, 0, stream>>>(pA, s, sd, N);
    k_histB  <<<CB * RB, 1024, 0, stream>>>(row, col, sd, pB, E, N);
    k_out    <<<(N + 255) / 256, 256, 0, stream>>>(pB, sd, a2, bias, out, N);
}

// Round 11
// 35.231 us; speedup vs baseline: 1.0538x; 1.0538x over previous
//
#include <hip/hip_runtime.h>

#define DIM 128
#define CA  32          // edge chunks, degree histogram
#define RA  2           // node ranges (u16-packed, 25000 = 50KB LDS)
#define NA  25000
#define HB  (CA * RA)   // 64 hist blocks in k1
#define CB  32          // edge chunks, weighted scatter
#define RB  8           // node ranges (2 x 6250 f32 = 50KB LDS)
#define NB  6250

typedef float vfloat4 __attribute__((ext_vector_type(4)));   // native vec for NT store

// K1 (fused): blocks [0,HB) build the u16-packed degree histogram of col
// (int4 edge scan); remaining blocks compute s[i] = dot(x[i], a1).
__global__ __launch_bounds__(1024) void k1_hist_s(
        const float* __restrict__ x, const float* __restrict__ a1,
        const int* __restrict__ col, ushort* __restrict__ pA,
        float* __restrict__ s, int E, int N) {
    __shared__ unsigned h[NA / 2];            // 50KB
    if (blockIdx.x < HB) {
        int c  = blockIdx.x % CA;
        int rg = blockIdx.x / CA;
        int lo = rg * NA;
        for (int j = threadIdx.x; j < NA / 2; j += 1024) h[j] = 0u;
        __syncthreads();
        int per = (((E + CA - 1) / CA) + 3) & ~3;        // x4-aligned chunks
        int e0 = c * per;
        int e1 = e0 + per; if (e1 > E) e1 = E;
        for (int e = e0 + threadIdx.x * 4; e < e1; e += 1024 * 4) {
            if (e + 4 <= e1) {
                int4 cv = *(const int4*)(col + e);
                unsigned i0 = (unsigned)(cv.x - lo), i1 = (unsigned)(cv.y - lo);
                unsigned i2 = (unsigned)(cv.z - lo), i3 = (unsigned)(cv.w - lo);
                if (i0 < (unsigned)NA) atomicAdd(&h[i0 >> 1], 1u << ((i0 & 1) * 16));
                if (i1 < (unsigned)NA) atomicAdd(&h[i1 >> 1], 1u << ((i1 & 1) * 16));
                if (i2 < (unsigned)NA) atomicAdd(&h[i2 >> 1], 1u << ((i2 & 1) * 16));
                if (i3 < (unsigned)NA) atomicAdd(&h[i3 >> 1], 1u << ((i3 & 1) * 16));
            } else {
                for (int ee = e; ee < e1; ++ee) {
                    unsigned idx = (unsigned)(col[ee] - lo);
                    if (idx < (unsigned)NA)
                        atomicAdd(&h[idx >> 1], 1u << ((idx & 1) * 16));
                }
            }
        }
        __syncthreads();
        unsigned* dst = (unsigned*)(pA + (size_t)c * N + lo);   // lo, N even
        for (int j = threadIdx.x; j < NA / 2; j += 1024) dst[j] = h[j];
    } else {
        int lw   = threadIdx.x >> 6;          // 16 waves, 2 rows each
        int lane = threadIdx.x & 63;
        int j    = lane & 31;
        int r = ((int)blockIdx.x - HB) * 32 + lw * 2 + (lane >> 5);
        if (r >= N) return;
        float4 xv = ((const float4*)x)[(size_t)r * 32 + j];
        float4 av = ((const float4*)a1)[j];
        float p = xv.x * av.x + xv.y * av.y + xv.z * av.z + xv.w * av.w;
        #pragma unroll
        for (int off = 16; off > 0; off >>= 1)
            p += __shfl_xor(p, off, 64);
        if (j == 0) s[r] = p;
    }
}

// K2: deg = 1 + sum_c pA (u32-packed, 2 nodes/thread); sd = (dis, dis*s)
__global__ void k_combine(const ushort* __restrict__ pA, const float* __restrict__ s,
                          float2* __restrict__ sd, int N) {
    int i2 = blockIdx.x * blockDim.x + threadIdx.x;
    if (i2 >= N / 2) return;
    unsigned d0 = 1u, d1 = 1u;                // self-loops
    #pragma unroll 8
    for (int c = 0; c < CA; ++c) {
        unsigned w = *(const unsigned*)&pA[(size_t)c * N + 2 * i2];
        d0 += w & 0xffffu; d1 += w >> 16;
    }
    float dv0 = rsqrtf((float)d0), dv1 = rsqrtf((float)d1);
    sd[2 * i2]     = make_float2(dv0, dv0 * s[2 * i2]);
    sd[2 * i2 + 1] = make_float2(dv1, dv1 * s[2 * i2 + 1]);
}

// K3: weighted scatter, int4 edge scan. Block (c,rg): LDS accumulate
// up += dis[c], vp += sdis[c] for edges with row in range; coalesced writeback.
__global__ __launch_bounds__(1024) void k_histB(const int* __restrict__ row,
                                                const int* __restrict__ col,
                                                const float2* __restrict__ sd,
                                                float2* __restrict__ pB,
                                                int E, int N) {
    __shared__ float up[NB];
    __shared__ float vp[NB];
    int c  = blockIdx.x % CB;
    int rg = blockIdx.x / CB;
    int lo = rg * NB;
    for (int j = threadIdx.x; j < NB; j += 1024) { up[j] = 0.f; vp[j] = 0.f; }
    __syncthreads();
    int per = (((E + CB - 1) / CB) + 3) & ~3;
    int e0 = c * per;
    int e1 = e0 + per; if (e1 > E) e1 = E;
    for (int e = e0 + threadIdx.x * 4; e < e1; e += 1024 * 4) {
        if (e + 4 <= e1) {
            int4 rv = *(const int4*)(row + e);
            int4 cv = *(const int4*)(col + e);
            unsigned i0 = (unsigned)(rv.x - lo), i1 = (unsigned)(rv.y - lo);
            unsigned i2 = (unsigned)(rv.z - lo), i3 = (unsigned)(rv.w - lo);
            if (i0 < (unsigned)NB) { float2 v = sd[cv.x]; atomicAdd(&up[i0], v.x); atomicAdd(&vp[i0], v.y); }
            if (i1 < (unsigned)NB) { float2 v = sd[cv.y]; atomicAdd(&up[i1], v.x); atomicAdd(&vp[i1], v.y); }
            if (i2 < (unsigned)NB) { float2 v = sd[cv.z]; atomicAdd(&up[i2], v.x); atomicAdd(&vp[i2], v.y); }
            if (i3 < (unsigned)NB) { float2 v = sd[cv.w]; atomicAdd(&up[i3], v.x); atomicAdd(&vp[i3], v.y); }
        } else {
            for (int ee = e; ee < e1; ++ee) {
                unsigned idx = (unsigned)(row[ee] - lo);
                if (idx < (unsigned)NB) {
                    float2 v = sd[col[ee]];
                    atomicAdd(&up[idx], v.x);
                    atomicAdd(&vp[idx], v.y);
                }
            }
        }
    }
    __syncthreads();
    int len = N - lo; if (len > NB) len = NB;
    float2* dst = pB + (size_t)c * N + lo;
    for (int j = threadIdx.x; j < len; j += 1024)
        dst[j] = make_float2(up[j], vp[j]);
}

// K4: two-phase. Phase 1: thread i reduces node i over CB copies (coalesced),
// T/W -> LDS. Phase 2: 32-lane groups write whole 512B rows as float4
// (non-temporal: out is never re-read, keep L2/L3 for pB/edges).
__global__ __launch_bounds__(256) void k_out(
        const float2* __restrict__ pB, const float2* __restrict__ sd,
        const float* __restrict__ a2, const float* __restrict__ bias,
        float* __restrict__ out, int N) {
    __shared__ float sT[256];
    __shared__ float sW[256];
    int base = blockIdx.x * 256;
    int i = base + threadIdx.x;
    if (i < N) {
        float su = 0.f, sv = 0.f;
        #pragma unroll 8
        for (int c = 0; c < CB; ++c) {
            float2 p = pB[(size_t)c * N + i];
            su += p.x; sv += p.y;
        }
        float2 d = sd[i];
        sT[threadIdx.x] = d.x * (sv + d.y);   // + self-loop dis*sdis
        sW[threadIdx.x] = d.x * (su + d.x);   // + self-loop dis*dis
    }
    __syncthreads();
    int j   = threadIdx.x & 31;
    int grp = threadIdx.x >> 5;               // 8 groups of 32 lanes
    float4 a2v = ((const float4*)a2)[j];
    float4 bv  = ((const float4*)bias)[j];
    #pragma unroll 4
    for (int rep = 0; rep < 32; ++rep) {
        int rl = rep * 8 + grp;
        int node = base + rl;
        if (node >= N) break;
        float T = sT[rl], W = sW[rl];
        vfloat4 o;
        o.x = a2v.x * T + bv.x * W;
        o.y = a2v.y * T + bv.y * W;
        o.z = a2v.z * T + bv.z * W;
        o.w = a2v.w * T + bv.w * W;
        __builtin_nontemporal_store(o, (vfloat4*)out + (size_t)node * 32 + j);
    }
}

extern "C" void kernel_launch(void* const* d_in, const int* in_sizes, int n_in,
                              void* d_out, int out_size, void* d_ws, size_t ws_size,
                              hipStream_t stream) {
    const float* x    = (const float*)d_in[0];
    const int*   ei   = (const int*)d_in[1];
    const float* a1   = (const float*)d_in[2];
    const float* a2   = (const float*)d_in[3];
    const float* bias = (const float*)d_in[4];
    float* out = (float*)d_out;

    int N = in_sizes[0] / DIM;   // 50000
    int E = in_sizes[1] / 2;     // 600000
    const int* row = ei;         // edge_index[0]
    const int* col = ei + E;     // edge_index[1]

    // workspace: s[N] f32, sd[N] float2, pA[CA*N] u16, pB[CB*N] float2 (~16.6MB)
    float*  s  = (float*)d_ws;
    float2* sd = (float2*)(s + N);
    ushort* pA = (ushort*)(sd + N);
    float2* pB = (float2*)(pA + (size_t)CA * N);

    int s_blocks = (N + 31) / 32;             // 32 rows per 1024-thread block
    k1_hist_s<<<HB + s_blocks, 1024, 0, stream>>>(x, a1, col, pA, s, E, N);
    k_combine<<<(N / 2 + 255) / 256, 256, 0, stream>>>(pA, s, sd, N);
    k_histB  <<<CB * RB, 1024, 0, stream>>>(row, col, sd, pB, E, N);
    k_out    <<<(N + 255) / 256, 256, 0, stream>>>(pB, sd, a2, bias, out, N);
}